// Round 4
// baseline (47194.156 us; speedup 1.0000x reference)
//
#include <hip/hip_runtime.h>
#include <math.h>

// MPNN on MI355X. R4: (a) fp32 global atomics eliminated via CSR-sorted edge
// processing + in-kernel block-level segmented reduction (plain stores for
// block-interior segments, atomics only for block-straddling runs);
// (b) GRU rebuilt: block=64/grid=2000, sequential-gate register scheme,
// in-place h update (no double buffer) -> workspace ~138MB (fits for sure).

#define DDIM 128
#define NTOT 128000
#define HBYTES 65536000ULL   // 128000*128*4

__device__ __forceinline__ float gelu_exact(float x) {
    return 0.5f * x * (1.0f + erff(x * 0.70710678118654752440f));
}
__device__ __forceinline__ float sigmoidf_(float x) {
    return 1.0f / (1.0f + expf(-x));
}

__global__ __launch_bounds__(256) void embed_kernel(
    const int* __restrict__ inp, const float* __restrict__ table,
    float* __restrict__ h)
{
    int gid = blockIdx.x * 256 + threadIdx.x;
    if (gid >= NTOT * 32) return;
    int row = gid >> 5;
    int q   = gid & 31;
    int b   = row / 4000;
    int n   = (row % 4000) % 1000;
    int e   = inp[b * 1000 + n];
    ((float4*)h)[gid] = ((const float4*)table)[e * 32 + q];
}

__global__ __launch_bounds__(256) void hist_kernel(
    const int* __restrict__ ni, const int* __restrict__ bi, int E,
    int* __restrict__ deg)
{
    int g = blockIdx.x * 256 + threadIdx.x;
    if (g < E)          atomicAdd(&deg[bi[g]], 1);
    else if (g < 2 * E) atomicAdd(&deg[ni[g - E]], 1);
}

__global__ __launch_bounds__(256) void blockscan_kernel(
    const int* __restrict__ deg, int* __restrict__ offp, int* __restrict__ bsum)
{
    __shared__ int s[256];
    int tid = threadIdx.x;
    int i = blockIdx.x * 256 + tid;
    int v = deg[i];
    s[tid] = v;
    __syncthreads();
    for (int off = 1; off < 256; off <<= 1) {
        int t = (tid >= off) ? s[tid - off] : 0;
        __syncthreads();
        s[tid] += t;
        __syncthreads();
    }
    offp[i] = s[tid] - v;
    if (tid == 255) bsum[blockIdx.x] = s[255];
}

__global__ __launch_bounds__(512) void bscan_kernel(
    const int* __restrict__ bsum, int* __restrict__ bexc, int nb)
{
    __shared__ int s[512];
    int t = threadIdx.x;
    int v = (t < nb) ? bsum[t] : 0;
    s[t] = v;
    __syncthreads();
    for (int off = 1; off < 512; off <<= 1) {
        int u = (t >= off) ? s[t - off] : 0;
        __syncthreads();
        s[t] += u;
        __syncthreads();
    }
    if (t < nb) bexc[t] = s[t] - v;
}

// writes elist[slot]=g and slotseg[slot]=seg for each directed edge g
__global__ __launch_bounds__(256) void fill_kernel(
    const int* __restrict__ ni, const int* __restrict__ bi, int E,
    const int* __restrict__ offp, const int* __restrict__ bexc,
    int* __restrict__ cursor, int* __restrict__ elist, int* __restrict__ slotseg)
{
    int g = blockIdx.x * 256 + threadIdx.x;
    if (g >= 2 * E) return;
    int seg = (g < E) ? bi[g] : ni[g - E];
    int pos = atomicAdd(&cursor[seg], 1);
    int slot = offp[seg] + bexc[seg >> 8] + pos;
    elist[slot] = g;
    slotseg[slot] = seg;
}

// Edge MLP over CSR-sorted slots with fused block-level segmented reduction.
// slot -> g=elist[slot]; g<E: x=[h[ni]||h[bi]] seg=bi; g>=E: x=[h[bi]||h[ni]] seg=ni.
__global__ __launch_bounds__(256, 3) void edge_mlp_csr_kernel(
    const float* __restrict__ h,
    const int* __restrict__ ni, const int* __restrict__ bi, int E,
    const int* __restrict__ elist, const int* __restrict__ slotseg,
    const float* __restrict__ Win,  const float* __restrict__ bin,
    const float* __restrict__ Whid, const float* __restrict__ bhid,
    const float* __restrict__ Wout, const float* __restrict__ bout,
    float* __restrict__ sbuf)
{
    __shared__ float w[4096];          // 16KB weight chunk
    __shared__ float scat[16 * 68];    // 4.35KB transpose batch (stride 68, b128-aligned)
    __shared__ int   segLDS[256];
    __shared__ int   segedge[2];       // [0]=seg before block, [1]=seg after block
    const int tid  = threadIdx.x;
    const int lane = tid & 63;
    const int wv   = tid >> 6;
    const int s0   = blockIdx.x * 256;
    const int slot = s0 + tid;

    const int seg = slotseg[slot];               // -1 for padded slots
    const int g   = (seg >= 0) ? elist[slot] : 0;
    int first = 0, second = 0;
    if (seg >= 0) {
        if (g < E) { first = ni[g];     second = bi[g];     }
        else       { first = bi[g - E]; second = ni[g - E]; }
    }
    segLDS[tid] = seg;
    if (tid == 0) segedge[0] = slotseg[s0 - 1];      // padded array: -1 at index -1
    if (tid == 1) segedge[1] = slotseg[s0 + 256];

    const float* rowp0 = h + (size_t)first  * DDIM;
    const float* rowp1 = h + (size_t)second * DDIM;

    // ---- stage 1: x[256] @ W_in[256x64] + b_in, gelu; 4 chunks ----
    float hcur[64];
    #pragma unroll
    for (int j = 0; j < 64; ++j) hcur[j] = bin[j];

    for (int c = 0; c < 4; ++c) {
        const float4* xb = (const float4*)((c < 2) ? rowp0 : rowp1) + (c & 1) * 16;
        float4 xv[8];
        #pragma unroll
        for (int q = 0; q < 8; ++q) xv[q] = xb[q];
        __syncthreads();
        for (int i4 = tid; i4 < 1024; i4 += 256)
            ((float4*)w)[i4] = ((const float4*)(Win + c * 4096))[i4];
        __syncthreads();
        #pragma unroll
        for (int q = 0; q < 8; ++q) {
            #pragma unroll
            for (int kk = 0; kk < 4; ++kk) {
                const float xk = (&xv[q].x)[kk];
                const float* wr = &w[(q * 4 + kk) * 64];
                #pragma unroll
                for (int j = 0; j < 64; ++j) hcur[j] = fmaf(xk, wr[j], hcur[j]);
            }
        }
        #pragma unroll
        for (int q = 0; q < 8; ++q) xv[q] = xb[8 + q];
        #pragma unroll
        for (int q = 0; q < 8; ++q) {
            #pragma unroll
            for (int kk = 0; kk < 4; ++kk) {
                const float xk = (&xv[q].x)[kk];
                const float* wr = &w[(32 + q * 4 + kk) * 64];
                #pragma unroll
                for (int j = 0; j < 64; ++j) hcur[j] = fmaf(xk, wr[j], hcur[j]);
            }
        }
    }
    #pragma unroll
    for (int j = 0; j < 64; ++j) hcur[j] = gelu_exact(hcur[j]);

    // ---- 3 hidden layers 64x64 ----
    for (int L = 0; L < 3; ++L) {
        __syncthreads();
        for (int i4 = tid; i4 < 1024; i4 += 256)
            ((float4*)w)[i4] = ((const float4*)(Whid + L * 4096))[i4];
        __syncthreads();
        float acc[64];
        #pragma unroll
        for (int j = 0; j < 64; ++j) acc[j] = bhid[L * 64 + j];
        #pragma unroll
        for (int k = 0; k < 64; ++k) {
            const float xk = hcur[k];
            const float* wr = &w[k * 64];
            #pragma unroll
            for (int j = 0; j < 64; ++j) acc[j] = fmaf(xk, wr[j], acc[j]);
        }
        #pragma unroll
        for (int j = 0; j < 64; ++j) hcur[j] = gelu_exact(acc[j]);
    }

    // ---- output layer (two 64-col halves) + fused segmented reduction ----
    for (int half = 0; half < 2; ++half) {
        __syncthreads();
        for (int i4 = tid; i4 < 1024; i4 += 256) {
            int k = i4 >> 4, jq = i4 & 15;
            ((float4*)w)[i4] = *(const float4*)(Wout + k * 128 + half * 64 + jq * 4);
        }
        __syncthreads();
        float acc[64];
        #pragma unroll
        for (int j = 0; j < 64; ++j) acc[j] = bout[half * 64 + j];
        #pragma unroll
        for (int k = 0; k < 64; ++k) {
            const float xk = hcur[k];
            const float* wr = &w[k * 64];
            #pragma unroll
            for (int j = 0; j < 64; ++j) acc[j] = fmaf(xk, wr[j], acc[j]);
        }

        // segmented reduction over the block's 256 sorted rows.
        int   runSeg = -2;
        float runacc = 0.0f;
        bool  leftC  = true;
        for (int b = 0; b < 16; ++b) {
            __syncthreads();                       // guard scat reuse
            if ((tid >> 4) == b) {
                float4* dp = (float4*)&scat[(tid & 15) * 68];
                #pragma unroll
                for (int q = 0; q < 16; ++q)
                    dp[q] = make_float4(acc[q*4], acc[q*4+1], acc[q*4+2], acc[q*4+3]);
            }
            __syncthreads();
            if (wv == 0) {
                for (int r = 0; r < 16; ++r) {
                    const int rowi = b * 16 + r;
                    const int sg = segLDS[rowi];
                    const float v = scat[r * 68 + lane];
                    if (sg != runSeg) {
                        if (runSeg >= 0) {         // emit: right-closed (seg changed)
                            float* p = sbuf + (size_t)runSeg * DDIM + half * 64 + lane;
                            if (leftC) *p = runacc;
                            else       atomicAdd(p, runacc);
                        }
                        runSeg = sg;
                        runacc = v;
                        leftC  = (rowi == 0) ? (segedge[0] != sg) : true;
                    } else {
                        runacc += v;
                    }
                }
            }
        }
        if (wv == 0 && runSeg >= 0) {              // tail
            const bool rightC = (segedge[1] != runSeg);
            float* p = sbuf + (size_t)runSeg * DDIM + half * 64 + lane;
            if (leftC && rightC) *p = runacc;
            else                 atomicAdd(p, runacc);
        }
        __syncthreads();
    }
}

// In-place GRU (keras reset_after). block=64 (one wave), grid=2000.
// Sequential-gate scheme; half-0 output parked in LDS, then h overwritten.
#define GRU_PASS(ACC, ROWP, W, CB, SCALE)                                      \
    for (int s = 0; s < 2; ++s) {                                              \
        __syncthreads();                                                       \
        for (int i4 = tid; i4 < 1024; i4 += 64) {                              \
            int kk = i4 >> 4, jq = i4 & 15;                                    \
            ((float4*)w)[i4] =                                                 \
                *((const float4*)((W) + (s * 64 + kk) * 384 + (CB)) + jq);     \
        }                                                                      \
        __syncthreads();                                                       \
        const float4* rp4 = (const float4*)(ROWP) + s * 16;                    \
        _Pragma("unroll 2")                                                    \
        for (int k4 = 0; k4 < 16; ++k4) {                                      \
            float4 xv4 = rp4[k4];                                              \
            _Pragma("unroll")                                                  \
            for (int kk = 0; kk < 4; ++kk) {                                   \
                float xk = (&xv4.x)[kk] * (SCALE);                             \
                const float* wr = &w[(k4 * 4 + kk) * 64];                      \
                _Pragma("unroll")                                              \
                for (int j = 0; j < 64; ++j) ACC[j] = fmaf(xk, wr[j], ACC[j]); \
            }                                                                  \
        }                                                                      \
    }

__global__ __launch_bounds__(64) void gru_kernel(
    float* __restrict__ h, const float* __restrict__ sbuf,
    const int* __restrict__ deg,
    const float* __restrict__ Wx, const float* __restrict__ Wh,
    const float* __restrict__ bi, const float* __restrict__ br)
{
    __shared__ float w[4096];          // 16KB weight stage
    __shared__ float obuf[64 * 68];    // half-0 outputs, stride 68 (b128-aligned)
    const int tid  = threadIdx.x;
    const int node = blockIdx.x * 64 + tid;
    const float cinv = 1.0f / fmaxf((float)deg[node], 1.0f);
    const float* mrow = sbuf + (size_t)node * DDIM;
    float*       hrow = h    + (size_t)node * DDIM;

    for (int half = 0; half < 2; ++half) {
        const int cb = half * 64;
        // r_pre
        float rv[64];
        #pragma unroll
        for (int j = 0; j < 64; ++j) rv[j] = bi[128 + cb + j] + br[128 + cb + j];
        GRU_PASS(rv, mrow, Wx, 128 + cb, cinv)
        GRU_PASS(rv, hrow, Wh, 128 + cb, 1.0f)
        // hh
        float hh[64];
        #pragma unroll
        for (int j = 0; j < 64; ++j) hh[j] = br[256 + cb + j];
        GRU_PASS(hh, hrow, Wh, 256 + cb, 1.0f)
        // t = sigmoid(r)*hh + bi_h ; += m@Wx_h ; cand = tanh(t)
        #pragma unroll
        for (int j = 0; j < 64; ++j)
            rv[j] = sigmoidf_(rv[j]) * hh[j] + bi[256 + cb + j];
        GRU_PASS(rv, mrow, Wx, 256 + cb, cinv)
        #pragma unroll
        for (int j = 0; j < 64; ++j) rv[j] = tanhf(rv[j]);
        // z
        #pragma unroll
        for (int j = 0; j < 64; ++j) hh[j] = bi[cb + j] + br[cb + j];
        GRU_PASS(hh, mrow, Wx, cb, cinv)
        GRU_PASS(hh, hrow, Wh, cb, 1.0f)
        // blend
        float4 hc4[16];
        #pragma unroll
        for (int q = 0; q < 16; ++q) hc4[q] = ((const float4*)hrow)[half * 16 + q];
        if (half == 0) {
            float4* op = (float4*)&obuf[tid * 68];
            #pragma unroll
            for (int q = 0; q < 16; ++q) {
                float4 o;
                #pragma unroll
                for (int kk = 0; kk < 4; ++kk) {
                    int j = q * 4 + kk;
                    float z = sigmoidf_(hh[j]);
                    (&o.x)[kk] = z * (&hc4[q].x)[kk] + (1.0f - z) * rv[j];
                }
                op[q] = o;
            }
        } else {
            // write half-1 directly (nothing reads h after this point)
            #pragma unroll
            for (int q = 0; q < 16; ++q) {
                float4 o;
                #pragma unroll
                for (int kk = 0; kk < 4; ++kk) {
                    int j = q * 4 + kk;
                    float z = sigmoidf_(hh[j]);
                    (&o.x)[kk] = z * (&hc4[q].x)[kk] + (1.0f - z) * rv[j];
                }
                ((float4*)hrow)[16 + q] = o;
            }
            // flush parked half-0
            const float4* op = (const float4*)&obuf[tid * 68];
            #pragma unroll
            for (int q = 0; q < 16; ++q) ((float4*)hrow)[q] = op[q];
        }
    }
}

__global__ __launch_bounds__(64, 3) void readout_kernel(
    const float* __restrict__ h,
    const float* __restrict__ Win,  const float* __restrict__ bin,
    const float* __restrict__ Whid, const float* __restrict__ bhid,
    const float* __restrict__ Wout, const float* __restrict__ bout,
    float* __restrict__ out)
{
    __shared__ float w[4096];
    const int tid = threadIdx.x;
    const int row = blockIdx.x * 64 + tid;        // 0..31999
    const int b = row / 1000, n = row % 1000;
    const float4* xrow = (const float4*)(h + ((size_t)b * 4000 + n) * DDIM);

    float hcur[64];
    #pragma unroll
    for (int j = 0; j < 64; ++j) hcur[j] = bin[j];

    for (int c = 0; c < 2; ++c) {
        __syncthreads();
        for (int i4 = tid; i4 < 1024; i4 += 64)
            ((float4*)w)[i4] = ((const float4*)(Win + c * 4096))[i4];
        __syncthreads();
        #pragma unroll
        for (int k4 = 0; k4 < 16; ++k4) {
            float4 xv = xrow[c * 16 + k4];
            #pragma unroll
            for (int kk = 0; kk < 4; ++kk) {
                float xk = (&xv.x)[kk];
                const float* wr = &w[(k4 * 4 + kk) * 64];
                #pragma unroll
                for (int j = 0; j < 64; ++j) hcur[j] = fmaf(xk, wr[j], hcur[j]);
            }
        }
    }
    #pragma unroll
    for (int j = 0; j < 64; ++j) hcur[j] = gelu_exact(hcur[j]);

    for (int L = 0; L < 3; ++L) {
        __syncthreads();
        for (int i4 = tid; i4 < 1024; i4 += 64)
            ((float4*)w)[i4] = ((const float4*)(Whid + L * 4096))[i4];
        __syncthreads();
        float acc[64];
        #pragma unroll
        for (int j = 0; j < 64; ++j) acc[j] = bhid[L * 64 + j];
        #pragma unroll
        for (int k = 0; k < 64; ++k) {
            float xk = hcur[k];
            const float* wr = &w[k * 64];
            #pragma unroll
            for (int j = 0; j < 64; ++j) acc[j] = fmaf(xk, wr[j], acc[j]);
        }
        #pragma unroll
        for (int j = 0; j < 64; ++j) hcur[j] = gelu_exact(acc[j]);
    }

    __syncthreads();
    for (int i = tid; i < 640; i += 64) w[i] = Wout[i];
    __syncthreads();

    float acc[10];
    #pragma unroll
    for (int p = 0; p < 10; ++p) acc[p] = bout[p];
    #pragma unroll
    for (int k = 0; k < 64; ++k) {
        float xk = hcur[k];
        #pragma unroll
        for (int p = 0; p < 10; ++p) acc[p] = fmaf(xk, w[k * 10 + p], acc[p]);
    }
    #pragma unroll
    for (int p = 0; p < 10; ++p) out[(size_t)row * 10 + p] = acc[p];
}

extern "C" void kernel_launch(void* const* d_in, const int* in_sizes, int n_in,
                              void* d_out, int out_size, void* d_ws, size_t ws_size,
                              hipStream_t stream) {
    const int*   node_inputs = (const int*)d_in[0];
    const int*   ni_int = (const int*)d_in[1];
    const int*   bi_int = (const int*)d_in[2];
    const int*   ni_tmp = (const int*)d_in[3];
    const int*   bi_tmp = (const int*)d_in[4];
    const float* embed  = (const float*)d_in[5];
    const float* mWin   = (const float*)d_in[6];
    const float* mbin   = (const float*)d_in[7];
    const float* mWhid  = (const float*)d_in[8];
    const float* mbhid  = (const float*)d_in[9];
    const float* mWout  = (const float*)d_in[10];
    const float* mbout  = (const float*)d_in[11];
    const float* roWin  = (const float*)d_in[12];
    const float* robin  = (const float*)d_in[13];
    const float* roWhid = (const float*)d_in[14];
    const float* robhid = (const float*)d_in[15];
    const float* roWout = (const float*)d_in[16];
    const float* robout = (const float*)d_in[17];
    const float* giWx = (const float*)d_in[18];
    const float* giWh = (const float*)d_in[19];
    const float* gibi = (const float*)d_in[20];
    const float* gibr = (const float*)d_in[21];
    const float* gtWx = (const float*)d_in[22];
    const float* gtWh = (const float*)d_in[23];
    const float* gtbi = (const float*)d_in[24];
    const float* gtbr = (const float*)d_in[25];
    float* out = (float*)d_out;

    const int E_INT = 200000, E_TMP = 96000;
    const int NSLOT_I = 400128;   // 1563*256 (padded), 400000 valid
    const int NSLOT_T = 192000;   // 750*256 exact

    char* ws = (char*)d_ws;
    float* hA   = (float*)(ws);
    float* sbuf = (float*)(ws + HBYTES);
    char*  ib   = ws + 2 * HBYTES;
    int* deg_i   = (int*)(ib);
    int* deg_t   = (int*)(ib + 512000);
    int* offp_i  = (int*)(ib + 1024000);
    int* offp_t  = (int*)(ib + 1536000);
    int* bexc_i  = (int*)(ib + 2048000);
    int* bexc_t  = (int*)(ib + 2052096);
    int* bsum    = (int*)(ib + 2056192);
    int* cursor  = (int*)(ib + 2060288);
    int* el_i    = (int*)(ib + 2572288);            // 400128*4
    int* el_t    = (int*)(ib + 4172800);            // 192000*4
    int* ssi_raw = (int*)(ib + 4940800);            // (1+400128+1)*4
    int* sst_raw = (int*)(ib + 6541320);            // (1+192000+1)*4
    int* ssi = ssi_raw + 1;
    int* sst = sst_raw + 1;

    embed_kernel<<<16000, 256, 0, stream>>>(node_inputs, embed, hA);

    hipMemsetAsync(deg_i, 0, NTOT * sizeof(int), stream);
    hipMemsetAsync(deg_t, 0, NTOT * sizeof(int), stream);
    hist_kernel<<<(2 * E_INT + 255) / 256, 256, 0, stream>>>(ni_int, bi_int, E_INT, deg_i);
    hist_kernel<<<(2 * E_TMP + 255) / 256, 256, 0, stream>>>(ni_tmp, bi_tmp, E_TMP, deg_t);

    hipMemsetAsync(ssi_raw, 0xFF, (size_t)(NSLOT_I + 2) * sizeof(int), stream);
    hipMemsetAsync(sst_raw, 0xFF, (size_t)(NSLOT_T + 2) * sizeof(int), stream);

    blockscan_kernel<<<500, 256, 0, stream>>>(deg_i, offp_i, bsum);
    bscan_kernel<<<1, 512, 0, stream>>>(bsum, bexc_i, 500);
    hipMemsetAsync(cursor, 0, NTOT * sizeof(int), stream);
    fill_kernel<<<(2 * E_INT + 255) / 256, 256, 0, stream>>>(
        ni_int, bi_int, E_INT, offp_i, bexc_i, cursor, el_i, ssi);

    blockscan_kernel<<<500, 256, 0, stream>>>(deg_t, offp_t, bsum);
    bscan_kernel<<<1, 512, 0, stream>>>(bsum, bexc_t, 500);
    hipMemsetAsync(cursor, 0, NTOT * sizeof(int), stream);
    fill_kernel<<<(2 * E_TMP + 255) / 256, 256, 0, stream>>>(
        ni_tmp, bi_tmp, E_TMP, offp_t, bexc_t, cursor, el_t, sst);

    for (int t = 0; t < 2; ++t) {
        hipMemsetAsync(sbuf, 0, HBYTES, stream);
        edge_mlp_csr_kernel<<<NSLOT_I / 256, 256, 0, stream>>>(
            hA, ni_int, bi_int, E_INT, el_i, ssi,
            mWin, mbin, mWhid, mbhid, mWout, mbout, sbuf);
        gru_kernel<<<NTOT / 64, 64, 0, stream>>>(
            hA, sbuf, deg_i, giWx, giWh, gibi, gibr);

        hipMemsetAsync(sbuf, 0, HBYTES, stream);
        edge_mlp_csr_kernel<<<NSLOT_T / 256, 256, 0, stream>>>(
            hA, ni_tmp, bi_tmp, E_TMP, el_t, sst,
            mWin, mbin, mWhid, mbhid, mWout, mbout, sbuf);
        gru_kernel<<<NTOT / 64, 64, 0, stream>>>(
            hA, sbuf, deg_t, gtWx, gtWh, gtbi, gtbr);
    }

    readout_kernel<<<500, 64, 0, stream>>>(
        hA, roWin, robin, roWhid, robhid, roWout, robout, out);
}